// Round 2
// baseline (138.678 us; speedup 1.0000x reference)
//
#include <hip/hip_runtime.h>
#include <math.h>

// N=32768 tokens, B=32 batches, S=1024 keys/batch, H=512, OUT=32.
#define H_DIM   512
#define OUT_DIM 32
#define S_LEN   1024
#define TOK_PER_BLOCK 64
#define THREADS 512           // 8 waves
#define NW 8

#if __has_builtin(__builtin_amdgcn_exp2f)
#define EXP2(x) __builtin_amdgcn_exp2f(x)
#else
#define EXP2(x) exp2f(x)
#endif

// Rank-2 collapse: score(i,j) = x_i^T (scale*Wq Wk^T) x_j  (2x2 M).
// Softmax shift uses analytic bound b_i = |u0|*max|x.0| + |u1|*max|x.1| >= row max
// (shift-invariant; gap small enough that exp2 stays in fp32 normal range).
// out_i = w_i @ Wv with w_i = softmax-weighted mean of x_j (2-vector).
// BN folds into ABC[h] = {Wv0[h]*g, Wv1[h]*g, beta[h]-mean[h]*g}, g = gamma*rsqrt(var+eps).
// y_i = PReLU(w0*A0 + w1*A1 + C) @ Wout + bout.

__global__ __launch_bounds__(THREADS, 4)
void fused_attn_kernel(const float* __restrict__ x,
                       const float* __restrict__ Wq,
                       const float* __restrict__ Wk,
                       const float* __restrict__ Wv,
                       const float* __restrict__ bn_gamma,
                       const float* __restrict__ bn_beta,
                       const float* __restrict__ bn_mean,
                       const float* __restrict__ bn_var,
                       const float* __restrict__ prelu_a,
                       const float* __restrict__ Wout,
                       const float* __restrict__ bout,
                       float* __restrict__ out)
{
    __shared__ float2 xs[S_LEN];          // 8 KB: batch's x
    __shared__ float4 ABC[H_DIM];         // 8 KB: {A0, A1, C, 0}
    __shared__ float  redl[NW][64], redw0[NW][64], redw1[NW][64]; // 6 KB
    __shared__ float  mred[NW][4];
    __shared__ float  mxred[NW][2];
    __shared__ float  yacc[TOK_PER_BLOCK][33];  // 8.4 KB, stride 33 -> conflict-free ds_add

    const int t    = threadIdx.x;
    const int lane = t & 63;
    const int q    = __builtin_amdgcn_readfirstlane(t >> 6);  // wave id 0..7, SGPR
    const int b    = blockIdx.x >> 4;     // 16 blocks per batch
    const int tile = blockIdx.x & 15;
    const float scale = 0.044194173824159216f;   // 1/sqrt(512)
    const float L2E   = 1.4426950408889634f;     // log2(e)

    // ---- zero yacc (b32, guarded grid-stride) ----
    float* yflat = &yacc[0][0];
    for (int i = t; i < TOK_PER_BLOCK * 33; i += THREADS) yflat[i] = 0.f;

    // ---- stage batch x into LDS + per-thread |x| component maxes ----
    const float4* xg = (const float4*)(x + (size_t)b * (S_LEN * 2));
    float4* xs4 = (float4*)xs;
    float4 xv = xg[t];                    // 512 threads x 1 float4 = 1024 float2
    xs4[t] = xv;
    float amax0 = fmaxf(fabsf(xv.x), fabsf(xv.z));
    float amax1 = fmaxf(fabsf(xv.y), fabsf(xv.w));

    // ---- fold BN into Wv: ABC[h] ----
    {
        int h = t;                        // 512 threads = 512 h
        float g = bn_gamma[h] * rsqrtf(bn_var[h] + 1e-5f);
        ABC[h] = make_float4(Wv[h] * g, Wv[H_DIM + h] * g,
                             bn_beta[h] - bn_mean[h] * g, 0.f);
    }

    // ---- M = Wq Wk^T partials (h = t) ----
    float m00, m01, m10, m11;
    {
        int h = t;
        float a0 = Wq[h], a1 = Wq[H_DIM + h];
        float b0 = Wk[h], b1 = Wk[H_DIM + h];
        m00 = a0 * b0; m01 = a0 * b1; m10 = a1 * b0; m11 = a1 * b1;
    }
    #pragma unroll
    for (int off = 32; off >= 1; off >>= 1) {
        m00 += __shfl_xor(m00, off);
        m01 += __shfl_xor(m01, off);
        m10 += __shfl_xor(m10, off);
        m11 += __shfl_xor(m11, off);
        amax0 = fmaxf(amax0, __shfl_xor(amax0, off));
        amax1 = fmaxf(amax1, __shfl_xor(amax1, off));
    }
    if (lane == 0) {
        mred[q][0] = m00; mred[q][1] = m01; mred[q][2] = m10; mred[q][3] = m11;
        mxred[q][0] = amax0; mxred[q][1] = amax1;
    }
    __syncthreads();   // sync1: xs, ABC, yacc-zero, mred, mxred all visible

    m00 = 0.f; m01 = 0.f; m10 = 0.f; m11 = 0.f;
    float mx0 = 0.f, mx1 = 0.f;
    #pragma unroll
    for (int w = 0; w < NW; ++w) {
        m00 += mred[w][0]; m01 += mred[w][1];
        m10 += mred[w][2]; m11 += mred[w][3];
        mx0 = fmaxf(mx0, mxred[w][0]);
        mx1 = fmaxf(mx1, mxred[w][1]);
    }
    m00 *= scale; m01 *= scale; m10 *= scale; m11 *= scale;

    // ---- per-token u (lane = token), bound b, fold log2e ----
    const float2 xt = xs[tile * TOK_PER_BLOCK + lane];
    const float u0 = fmaf(xt.x, m00, xt.y * m10);
    const float u1 = fmaf(xt.x, m01, xt.y * m11);
    const float bnd = fmaf(fabsf(u0), mx0, fabsf(u1) * mx1);
    const float u0L = u0 * L2E, u1L = u1 * L2E, nbL = -bnd * L2E;

    // ---- fused softmax pass: wave q covers keys [q*128, q*128+128) ----
    float l = 0.f, w0 = 0.f, w1 = 0.f;
    const float4* kv = xs4 + q * 64;      // 64 float4 = 128 keys
    #pragma unroll 4
    for (int i = 0; i < 64; ++i) {
        float4 k2 = kv[i];                // wave-uniform addr -> broadcast
        float e0 = EXP2(fmaf(u0L, k2.x, fmaf(u1L, k2.y, nbL)));
        float e1 = EXP2(fmaf(u0L, k2.z, fmaf(u1L, k2.w, nbL)));
        l += e0 + e1;
        w0 = fmaf(e0, k2.x, fmaf(e1, k2.z, w0));
        w1 = fmaf(e0, k2.y, fmaf(e1, k2.w, w1));
    }
    redl[q][lane] = l; redw0[q][lane] = w0; redw1[q][lane] = w1;
    __syncthreads();   // sync2

    l = 0.f; w0 = 0.f; w1 = 0.f;
    #pragma unroll
    for (int w = 0; w < NW; ++w) {
        l  += redl[w][lane];
        w0 += redw0[w][lane];
        w1 += redw1[w][lane];
    }
    const float inv = 1.0f / l;
    w0 *= inv; w1 *= inv;

    // ---- epilogue: wave q handles h in [q*64, q*64+64), lane = token ----
    const float ap = prelu_a[0];
    float y[OUT_DIM];
    #pragma unroll
    for (int o = 0; o < OUT_DIM; ++o) y[o] = 0.f;
    const int h0 = q * 64;
    #pragma unroll 2
    for (int hh = 0; hh < 64; ++hh) {
        int h = h0 + hh;                  // wave-uniform -> Wout rows via s_load
        float4 abc = ABC[h];              // broadcast b128
        float z = fmaf(w0, abc.x, fmaf(w1, abc.y, abc.z));
        float p = fmaxf(z, 0.f) + ap * fminf(z, 0.f);   // PReLU
        const float* wrow = Wout + h * OUT_DIM;
        #pragma unroll
        for (int o = 0; o < OUT_DIM; ++o)
            y[o] = fmaf(p, wrow[o], y[o]);
    }
    // conflict-free LDS float atomics (stride 33: bank = (lane+o) & 31)
    #pragma unroll
    for (int o = 0; o < OUT_DIM; ++o)
        atomicAdd(&yacc[lane][o], y[o]);
    __syncthreads();   // sync3

    // ---- bias + coalesced store: 64 tok x 32 out = 2048 floats ----
    {
        const size_t base = (size_t)(b * S_LEN + tile * TOK_PER_BLOCK) * OUT_DIM;
        int tok = t >> 3, o0 = (t & 7) * 4;      // thread t -> 4 consecutive outputs
        const float4 b4 = ((const float4*)bout)[t & 7];
        float4 v;
        v.x = yacc[tok][o0 + 0] + b4.x;
        v.y = yacc[tok][o0 + 1] + b4.y;
        v.z = yacc[tok][o0 + 2] + b4.z;
        v.w = yacc[tok][o0 + 3] + b4.w;
        *(float4*)(out + base + (size_t)t * 4) = v;
    }
}

extern "C" void kernel_launch(void* const* d_in, const int* in_sizes, int n_in,
                              void* d_out, int out_size, void* d_ws, size_t ws_size,
                              hipStream_t stream) {
    const float* x    = (const float*)d_in[0];
    const float* Wq   = (const float*)d_in[2];
    const float* Wk   = (const float*)d_in[3];
    const float* Wv   = (const float*)d_in[4];
    const float* gam  = (const float*)d_in[5];
    const float* bet  = (const float*)d_in[6];
    const float* mean = (const float*)d_in[7];
    const float* var  = (const float*)d_in[8];
    const float* pa   = (const float*)d_in[9];
    const float* Wout = (const float*)d_in[10];
    const float* bo   = (const float*)d_in[11];
    float* out = (float*)d_out;

    const int N = in_sizes[0] / 2;          // 32768 tokens
    const int blocks = N / TOK_PER_BLOCK;   // 512
    hipLaunchKernelGGL(fused_attn_kernel, dim3(blocks), dim3(THREADS), 0, stream,
                       x, Wq, Wk, Wv, gam, bet, mean, var, pa, Wout, bo, out);
}

// Round 3
// 97.348 us; speedup vs baseline: 1.4246x; 1.4246x over previous
//
#include <hip/hip_runtime.h>
#include <math.h>

// N=32768 tokens, B=32 batches, S=1024 keys/batch, H=512, OUT=32.
//
// Rank-2 collapse: score(i,j) = x_i^T (scale*Wq Wk^T) x_j  (2x2 M).
// w_i = softmax-weighted mean of x_j (2-vector); softmax shift via analytic
// bound b_i = |u0|*maxb|x.0| + |u1|*maxb|x.1| (per batch).
// BN folds into ABC[h] = {Wv0*g, Wv1*g, beta-mean*g}, g = gamma*rsqrt(var+eps).
// P[tok][h] = PReLU(w0*A0[h] + w1*A1[h] + C[h]);  y = P @ Wout + bout.
// Epilogue y = P@Wout is a 64x32x512 bf16 MFMA GEMM per block (16x16x32 frags):
//   A-frag: P, m=lane&15 (token), k=quad*8+j  (m120-verified layout)
//   B-frag: Wout pre-swizzled bf16 in d_ws so each lane reads its 8 bf16 as
//           one coalesced global_load_dwordx4
//   C/D:    col=lane&15 (out), row=quad*4+reg (token)  (m89/m91-verified)

#define H_DIM   512
#define OUT_DIM 32
#define S_LEN   1024
#define THREADS 256
#define NW 4

// ws layout (bytes)
#define WS_WOUT 0        // 32 KB: 32 frags x 64 lanes x 16 B bf16 B-fragments
#define WS_ABC  32768    // 8 KB: float4[512] {A0,A1,C,0}
#define WS_M    40960    // 16 B: scaled 2x2 M
#define WS_AMAX 40976    // 256 B: float2[32] per-batch {max|x0|, max|x1|}

#if __has_builtin(__builtin_amdgcn_exp2f)
#define EXP2(x) __builtin_amdgcn_exp2f(x)
#else
#define EXP2(x) exp2f(x)
#endif

typedef __attribute__((ext_vector_type(8))) short bf16x8;
typedef __attribute__((ext_vector_type(4))) float f32x4;

__device__ __forceinline__ unsigned int rne_bf16(float f) {
    unsigned int u = __float_as_uint(f);
    return (u + 0x7fffu + ((u >> 16) & 1u)) >> 16;
}
__device__ __forceinline__ unsigned int pack2bf16(float lo, float hi) {
    return rne_bf16(lo) | (rne_bf16(hi) << 16);
}

union frag_cast { unsigned int u[4]; int4 i4; bf16x8 v; };

// ---------------- setup: swizzle Wout->bf16 frags, fold BN, M, amax ----------
__global__ __launch_bounds__(256)
void setup_kernel(const float* __restrict__ x,
                  const float* __restrict__ Wq, const float* __restrict__ Wk,
                  const float* __restrict__ Wv,
                  const float* __restrict__ gam, const float* __restrict__ bet,
                  const float* __restrict__ mean, const float* __restrict__ var,
                  const float* __restrict__ Wout,
                  unsigned char* __restrict__ ws)
{
    const int t = threadIdx.x;
    if (blockIdx.x < 16) {
        // dst bf16-pair pi -> element d=2*pi: d = ((nt*16+s)*64 + l)*8 + j
        unsigned int* dst = (unsigned int*)(ws + WS_WOUT);
        #pragma unroll
        for (int k = 0; k < 2; ++k) {
            int pi = blockIdx.x * 512 + k * 256 + t;
            int d  = pi * 2;
            int fid = d >> 9;                 // nt*16+s, 0..31
            int l   = (d >> 3) & 63;
            int j   = d & 7;                  // even
            int nt  = fid >> 4;
            int s   = fid & 15;
            int h   = s * 32 + (l >> 4) * 8 + j;
            int o   = nt * 16 + (l & 15);
            float f0 = Wout[h * 32 + o];
            float f1 = Wout[(h + 1) * 32 + o];
            dst[pi] = pack2bf16(f0, f1);
        }
    } else {
        // ABC
        float4* abc = (float4*)(ws + WS_ABC);
        #pragma unroll
        for (int k = 0; k < 2; ++k) {
            int h = t + k * 256;
            float g = gam[h] * rsqrtf(var[h] + 1e-5f);
            abc[h] = make_float4(Wv[h] * g, Wv[H_DIM + h] * g,
                                 bet[h] - mean[h] * g, 0.f);
        }
        // M = scale * Wq Wk^T (wave 0 only)
        if (t < 64) {
            float m00 = 0.f, m01 = 0.f, m10 = 0.f, m11 = 0.f;
            #pragma unroll
            for (int k = 0; k < 8; ++k) {
                int h = t + k * 64;
                float a0 = Wq[h], a1 = Wq[H_DIM + h];
                float b0 = Wk[h], b1 = Wk[H_DIM + h];
                m00 = fmaf(a0, b0, m00); m01 = fmaf(a0, b1, m01);
                m10 = fmaf(a1, b0, m10); m11 = fmaf(a1, b1, m11);
            }
            #pragma unroll
            for (int off = 32; off >= 1; off >>= 1) {
                m00 += __shfl_xor(m00, off); m01 += __shfl_xor(m01, off);
                m10 += __shfl_xor(m10, off); m11 += __shfl_xor(m11, off);
            }
            if (t == 0) {
                const float scale = 0.044194173824159216f;  // 1/sqrt(512)
                float* m = (float*)(ws + WS_M);
                m[0] = m00 * scale; m[1] = m01 * scale;
                m[2] = m10 * scale; m[3] = m11 * scale;
            }
        }
        // per-batch amax: 8 threads per batch
        {
            int batch = t >> 3, sub = t & 7;
            const float4* xb = ((const float4*)x) + batch * 512;
            float a0 = 0.f, a1 = 0.f;
            for (int i = 0; i < 64; ++i) {
                float4 v = xb[sub + i * 8];
                a0 = fmaxf(a0, fmaxf(fabsf(v.x), fabsf(v.z)));
                a1 = fmaxf(a1, fmaxf(fabsf(v.y), fabsf(v.w)));
            }
            #pragma unroll
            for (int off = 4; off >= 1; off >>= 1) {
                a0 = fmaxf(a0, __shfl_xor(a0, off));
                a1 = fmaxf(a1, __shfl_xor(a1, off));
            }
            if (sub == 0)
                ((float2*)(ws + WS_AMAX))[batch] = make_float2(a0, a1);
        }
    }
}

// ---------------- main kernel ------------------------------------------------
__global__ __launch_bounds__(THREADS)
void fused_attn_kernel(const float* __restrict__ x,
                       const float* __restrict__ prelu_a,
                       const float* __restrict__ bout,
                       const unsigned char* __restrict__ ws,
                       float* __restrict__ out)
{
    __shared__ float2 xs[S_LEN];            // 8 KB
    __shared__ float4 abcs[H_DIM];          // 8 KB
    __shared__ float redl[NW][64], redw0[NW][64], redw1[NW][64]; // 3 KB

    const int t    = threadIdx.x;
    const int lane = t & 63;
    const int q    = __builtin_amdgcn_readfirstlane(t >> 6);  // wave id 0..3
    const int b    = blockIdx.x >> 4;
    const int tile = blockIdx.x & 15;

    // stage x and ABC into LDS
    const float4* xg = (const float4*)(x + (size_t)b * (S_LEN * 2));
    float4* xs4 = (float4*)xs;
    xs4[t]       = xg[t];
    xs4[t + 256] = xg[t + 256];
    const float4* abcg = (const float4*)(ws + WS_ABC);
    abcs[t]       = abcg[t];
    abcs[t + 256] = abcg[t + 256];

    const float* mp = (const float*)(ws + WS_M);
    const float m00 = mp[0], m01 = mp[1], m10 = mp[2], m11 = mp[3];
    const float2 am = ((const float2*)(ws + WS_AMAX))[b];
    __syncthreads();

    // per-token u (lane = block-relative token), analytic softmax bound
    const float2 xt = xs[tile * 64 + lane];
    const float u0 = fmaf(xt.x, m00, xt.y * m10);
    const float u1 = fmaf(xt.x, m01, xt.y * m11);
    const float L2E = 1.4426950408889634f;
    const float bnd = fmaf(fabsf(u0), am.x, fabsf(u1) * am.y);
    const float u0L = u0 * L2E, u1L = u1 * L2E, nbL = -bnd * L2E;

    // fused softmax pass: wave q covers keys [q*256, q*256+256)
    float l = 0.f, w0 = 0.f, w1 = 0.f;
    const float4* kv = ((const float4*)xs) + q * 128;
    #pragma unroll 4
    for (int i = 0; i < 128; ++i) {
        float4 k2 = kv[i];                  // wave-uniform addr -> broadcast
        float e0 = EXP2(fmaf(u0L, k2.x, fmaf(u1L, k2.y, nbL)));
        float e1 = EXP2(fmaf(u0L, k2.z, fmaf(u1L, k2.w, nbL)));
        l += e0 + e1;
        w0 = fmaf(e0, k2.x, fmaf(e1, k2.z, w0));
        w1 = fmaf(e0, k2.y, fmaf(e1, k2.w, w1));
    }
    redl[q][lane] = l; redw0[q][lane] = w0; redw1[q][lane] = w1;
    __syncthreads();
    l  = redl[0][lane]  + redl[1][lane]  + redl[2][lane]  + redl[3][lane];
    w0 = redw0[0][lane] + redw0[1][lane] + redw0[2][lane] + redw0[3][lane];
    w1 = redw1[0][lane] + redw1[1][lane] + redw1[2][lane] + redw1[3][lane];
    const float inv = 1.0f / l;
    w0 *= inv; w1 *= inv;

    // redistribute: wave q's MFMA tile = tokens q*16..q*16+15; m = lane&15
    const int src = q * 16 + (lane & 15);
    const float w0t = __shfl(w0, src);
    const float w1t = __shfl(w1, src);

    // ---- MFMA epilogue: y[16 tok x 32 out] = P[16 x 512] @ Wout[512 x 32] ----
    const float ap = prelu_a[0];
    const int quad = lane >> 4;
    f32x4 acc0 = {0.f, 0.f, 0.f, 0.f};
    f32x4 acc1 = {0.f, 0.f, 0.f, 0.f};
    const int4* bsrc = (const int4*)(ws + WS_WOUT);

    for (int s = 0; s < 16; ++s) {
        // B-frags: coalesced 16B/lane from pre-swizzled ws
        frag_cast bf0, bf1;
        bf0.i4 = bsrc[s * 64 + lane];
        bf1.i4 = bsrc[(16 + s) * 64 + lane];
        // A-frag: P for token m=lane&15, h = s*32 + quad*8 + j
        const int hbase = s * 32 + quad * 8;
        frag_cast af;
        #pragma unroll
        for (int jj = 0; jj < 4; ++jj) {
            float4 c0 = abcs[hbase + jj * 2];       // broadcast ds_read_b128
            float4 c1 = abcs[hbase + jj * 2 + 1];
            float z0 = fmaf(w0t, c0.x, fmaf(w1t, c0.y, c0.z));
            float z1 = fmaf(w0t, c1.x, fmaf(w1t, c1.y, c1.z));
            float p0 = fmaxf(z0, 0.f) + ap * fminf(z0, 0.f);   // PReLU
            float p1 = fmaxf(z1, 0.f) + ap * fminf(z1, 0.f);
            af.u[jj] = pack2bf16(p0, p1);
        }
        acc0 = __builtin_amdgcn_mfma_f32_16x16x32_bf16(af.v, bf0.v, acc0, 0, 0, 0);
        acc1 = __builtin_amdgcn_mfma_f32_16x16x32_bf16(af.v, bf1.v, acc1, 0, 0, 0);
    }

    // ---- store: D col=lane&15, row=quad*4+r ----
    const size_t base = (size_t)(b * S_LEN + tile * 64) * OUT_DIM;
    const int o0 = lane & 15;
    const float bo0 = bout[o0], bo1 = bout[16 + o0];
    #pragma unroll
    for (int r = 0; r < 4; ++r) {
        const int tt = q * 16 + quad * 4 + r;
        out[base + tt * 32 + o0]      = acc0[r] + bo0;
        out[base + tt * 32 + 16 + o0] = acc1[r] + bo1;
    }
}

extern "C" void kernel_launch(void* const* d_in, const int* in_sizes, int n_in,
                              void* d_out, int out_size, void* d_ws, size_t ws_size,
                              hipStream_t stream) {
    const float* x    = (const float*)d_in[0];
    const float* Wq   = (const float*)d_in[2];
    const float* Wk   = (const float*)d_in[3];
    const float* Wv   = (const float*)d_in[4];
    const float* gam  = (const float*)d_in[5];
    const float* bet  = (const float*)d_in[6];
    const float* mean = (const float*)d_in[7];
    const float* var  = (const float*)d_in[8];
    const float* pa   = (const float*)d_in[9];
    const float* Wout = (const float*)d_in[10];
    const float* bo   = (const float*)d_in[11];
    float* out = (float*)d_out;
    unsigned char* ws = (unsigned char*)d_ws;

    hipLaunchKernelGGL(setup_kernel, dim3(17), dim3(256), 0, stream,
                       x, Wq, Wk, Wv, gam, bet, mean, var, Wout, ws);

    const int N = in_sizes[0] / 2;          // 32768 tokens
    const int blocks = N / 64;              // 512
    hipLaunchKernelGGL(fused_attn_kernel, dim3(blocks), dim3(THREADS), 0, stream,
                       x, pa, bo, ws, out);
}